// Round 11
// baseline (4126.482 us; speedup 1.0000x reference)
//
#include <hip/hip_runtime.h>

#define LAYERS 6
#define BB 10
#define TT 2048
#define II 128
#define HH 256
#define DEPTH 8           // safe ring depth (power of 2)
#define FDEPTH 4          // fast ring depth (power of 2)
#define NTH 256
#define NROW 32           // gate rows per block (4 gates x 8 cols)
#define NCOL 8
#define SLOTU 1280        // u64 per layer-slot: 32 blocks x 40 tagged u64
#define KSTR 520          // hcB K-stride in bf16 (512 + 8 pad)
#define XSTR 136          // xlo K-stride in bf16 (128 + 8 pad)
#define RSTR 36           // red rloc-stride in floats

typedef unsigned long long u64;
typedef unsigned int u32;
typedef __attribute__((ext_vector_type(8))) short bf16x8;   // 8 bf16 = 4 VGPR
typedef __attribute__((ext_vector_type(4))) float f32x4;

#define MFMA16 __builtin_amdgcn_mfma_f32_16x16x32_bf16

struct __align__(16) Smem {
    short hcB[16][KSTR];     // bf16 [x/below-h | own-h] per batch row; rows 10..15 zero
    short xlo[16][XSTR];     // bf16 residual plane for layer-0 x (hi/lo split)
    float red[4][16][RSTR];  // per-wave K-partial gates: [wave][batch][rloc]
    float bias_s[NROW];
};

__device__ __forceinline__ float fsig(float x) { return 1.0f / (1.0f + __expf(-x)); }
__device__ __forceinline__ float ftanh(float x) {
    x = fminf(fmaxf(x, -15.0f), 15.0f);
    float e = __expf(2.0f * x);
    return (e - 1.0f) / (e + 1.0f);
}
__device__ __forceinline__ int ld_cnt(const int* p) {
    return __hip_atomic_load(p, __ATOMIC_RELAXED, __HIP_MEMORY_SCOPE_AGENT);
}
__device__ __forceinline__ void st_cnt(int* p, int v) {
    __hip_atomic_store(p, v, __ATOMIC_RELAXED, __HIP_MEMORY_SCOPE_AGENT);
}
__device__ __forceinline__ u64 ld_u64(const u64* p) {
    return __hip_atomic_load(p, __ATOMIC_RELAXED, __HIP_MEMORY_SCOPE_AGENT);
}
__device__ __forceinline__ void st_u64(u64* p, u64 v) {
    __hip_atomic_store(p, v, __ATOMIC_RELAXED, __HIP_MEMORY_SCOPE_AGENT);
}
// ---- XCD-local L2 exchange primitives ----
// producer: plain global_store -> lands in the XCD's shared L2 (stays dirty).
// consumer: sc0 load bypasses L1, reads the shared L2. Tags self-validate; the
// agent-scope safe ring is the correctness fallback under any block->XCD
// placement. R11: the agent safe store is DEFERRED to the top of the next step
// and issued AFTER the gather loads, so the first gather wait can use vmcnt(1)
// — the agent store-ack (newest in queue, in-order retirement) is excluded.
__device__ __forceinline__ void st_l2(u64* p, u64 v) {
    asm volatile("global_store_dwordx2 %0, %1, off" :: "v"(p), "v"(v) : "memory");
}
// issue 10 sc0 loads (base + i*1024B), NO wait: latency hides under A-phase
__device__ __forceinline__ void ld10_issue(u64 v[10], const u64* p) {
    const u64* p4 = p + 4 * 128;
    const u64* p8 = p + 8 * 128;
    asm volatile(
        "global_load_dwordx2 %0, %10, off sc0\n\t"
        "global_load_dwordx2 %1, %10, off offset:1024 sc0\n\t"
        "global_load_dwordx2 %2, %10, off offset:2048 sc0\n\t"
        "global_load_dwordx2 %3, %10, off offset:3072 sc0\n\t"
        "global_load_dwordx2 %4, %11, off sc0\n\t"
        "global_load_dwordx2 %5, %11, off offset:1024 sc0\n\t"
        "global_load_dwordx2 %6, %11, off offset:2048 sc0\n\t"
        "global_load_dwordx2 %7, %11, off offset:3072 sc0\n\t"
        "global_load_dwordx2 %8, %12, off sc0\n\t"
        "global_load_dwordx2 %9, %12, off offset:1024 sc0\n\t"
        : "=&v"(v[0]), "=&v"(v[1]), "=&v"(v[2]), "=&v"(v[3]), "=&v"(v[4]),
          "=&v"(v[5]), "=&v"(v[6]), "=&v"(v[7]), "=&v"(v[8]), "=&v"(v[9])
        : "v"(p), "v"(p4), "v"(p8)
        : "memory");
}
// first wait: vmcnt(1) — all 10 loads retired (they are older than the one
// deferred agent store); the store ack may still be outstanding.
__device__ __forceinline__ void ld10_wait1(u64 v[10]) {
    asm volatile("s_waitcnt vmcnt(1)"
        : "+v"(v[0]), "+v"(v[1]), "+v"(v[2]), "+v"(v[3]), "+v"(v[4]),
          "+v"(v[5]), "+v"(v[6]), "+v"(v[7]), "+v"(v[8]), "+v"(v[9]) :: "memory");
    __builtin_amdgcn_sched_barrier(0);
}
// retry wait: vmcnt(0) (the deferred store is oldest by then — harmless)
__device__ __forceinline__ void ld10_wait(u64 v[10]) {
    asm volatile("s_waitcnt vmcnt(0)"
        : "+v"(v[0]), "+v"(v[1]), "+v"(v[2]), "+v"(v[3]), "+v"(v[4]),
          "+v"(v[5]), "+v"(v[6]), "+v"(v[7]), "+v"(v[8]), "+v"(v[9]) :: "memory");
    __builtin_amdgcn_sched_barrier(0);
}
__device__ __forceinline__ u32 bf16r(float v) {           // RNE float->bf16 bits
    u32 x = __float_as_uint(v);
    return (x + 0x7FFFu + ((x >> 16) & 1u)) >> 16;
}
// pack order: low u32 half = h0 (even col), high half = h1 (odd col): consumer
// stores raw (u32)v into LDS and gets k-ascending bf16 pairs.
__device__ __forceinline__ u64 packh(float h0, float h1, u32 tag) {
    return ((u64)tag << 32) | ((u64)bf16r(h1) << 16) | (u64)bf16r(h0);
}
// u/40 exact for u < 262144
__device__ __forceinline__ int div40(int u) { return (int)(((unsigned)u * 52429u) >> 21); }

// back-pressure poll: all 32 ints on one 128B line >= tgt
__device__ __forceinline__ void poll32(const int* base, int tgt, bool sleep) {
    const int lane = threadIdx.x & 63;
    const int* p = base + (lane & 31);
    for (;;) {
        int v = ld_cnt(p);
        if (__ballot((lane < 32) && (v < tgt)) == 0) break;
        if (sleep) __builtin_amdgcn_s_sleep(2);
    }
    asm volatile("" ::: "memory");
}

// stage 4 fp32 x values -> bf16 hi plane + bf16 lo (residual) plane
__device__ __forceinline__ void stage_x(Smem& sm, int b, int c4, float4 xv) {
    const u32 h0 = bf16r(xv.x), h1 = bf16r(xv.y), h2 = bf16r(xv.z), h3 = bf16r(xv.w);
    *(u32*)&sm.hcB[b][c4]     = (h1 << 16) | h0;
    *(u32*)&sm.hcB[b][c4 + 2] = (h3 << 16) | h2;
    const u32 r0 = bf16r(xv.x - __uint_as_float(h0 << 16));
    const u32 r1 = bf16r(xv.y - __uint_as_float(h1 << 16));
    const u32 r2 = bf16r(xv.z - __uint_as_float(h2 << 16));
    const u32 r3 = bf16r(xv.w - __uint_as_float(h3 << 16));
    *(u32*)&sm.xlo[b][c4]     = (r1 << 16) | r0;
    *(u32*)&sm.xlo[b][c4 + 2] = (r3 << 16) | r2;
}

// NKT: 12 -> K=384 (layer 0), 16 -> K=512 (layers 1..5)
template <int NKT>
__device__ void run_layer(Smem& sm, int l, int s,
                          const float* __restrict__ x,
                          const float* __restrict__ h0,
                          const float* __restrict__ c0,
                          const float* __restrict__ Wih0,
                          const float* __restrict__ Wih,
                          const float* __restrict__ Whh,
                          const float* __restrict__ bih,
                          const float* __restrict__ bhh,
                          float* __restrict__ out,
                          int* flags, float* hring, u64* hfast)
{
    constexpr int K   = NKT * 32;
    constexpr int F   = K - HH;       // x-part size: 128 or 256
    constexpr int NKW = NKT / 4;      // K-tiles per wave (3 or 4)
    constexpr int XP  = NKW - 2;      // x-region K-tiles per wave (1 or 2)

    const int tid  = threadIdx.x;
    const int wave = tid >> 6;
    const int l15  = tid & 15;        // MFMA: A row / B col (batch) / C col
    const int kgrp = (tid >> 4) & 3;  // MFMA: K-group within tile
    const int eb   = tid >> 3;        // epilogue batch  (tid < 80)
    const int ej   = tid & 7;         // epilogue column (tid < 80)
    const bool pubL = (tid < 80) && ((ej & 1) == 0);   // 40 publishing lanes
    const int pidx = eb * 4 + (ej >> 1);               // u64 index within slot

    const float* WihL = (F == II) ? Wih0 : (Wih + (size_t)(l - 1) * 4 * HH * HH);
    const float* WhhL = Whh + (size_t)l * 4 * HH * HH;

    // ---- weight fragments, hi/lo split, VGPR-resident ----
    // wave w owns K-tiles {w + 4p}; p < XP is x-region, rest is h-region.
    bf16x8 whi[2][NKW], wlo[2][NKW];
    #pragma unroll
    for (int m = 0; m < 2; ++m) {
        const int rloc = m * 16 + l15;
        const int gr = (rloc >> 3) * HH + s * NCOL + (rloc & 7);
        const float* rowI = WihL + (size_t)gr * F;
        const float* rowH = WhhL + (size_t)gr * HH;
        #pragma unroll
        for (int p = 0; p < NKW; ++p) {
            const int kb = (wave + 4 * p) * 32 + kgrp * 8;   // multiple of 8; F%8==0
            const float* src = (kb < F) ? (rowI + kb) : (rowH + (kb - F));
            const float4 va = *(const float4*)src;
            const float4 vb = *(const float4*)(src + 4);
            const float v[8] = {va.x, va.y, va.z, va.w, vb.x, vb.y, vb.z, vb.w};
            #pragma unroll
            for (int j = 0; j < 8; ++j) {
                const u32 hi = bf16r(v[j]);
                whi[m][p][j] = (short)hi;
                wlo[m][p][j] = (short)bf16r(v[j] - __uint_as_float(hi << 16));
            }
        }
    }
    if (tid < NROW) {
        const int gr = (tid >> 3) * HH + s * NCOL + (tid & 7);
        sm.bias_s[tid] = bih[l * 4 * HH + gr] + bhh[l * 4 * HH + gr];
    }
    // c-state lives in a register: 80 lanes, 1 column each (b = eb, jj = ej)
    float creg = 0.0f;
    if (tid < 80)
        creg = c0[((size_t)l * BB + eb) * HH + s * NCOL + ej];
    {   // zero batch rows 10..15 (MFMA N=16 padding is inert; never written again)
        u32* z1 = (u32*)&sm.hcB[10][0];
        for (int i = tid; i < 6 * KSTR / 2; i += NTH) z1[i] = 0;
        u32* z2 = (u32*)&sm.xlo[10][0];
        for (int i = tid; i < 6 * XSTR / 2; i += NTH) z2[i] = 0;
    }

    u64* const ringu  = (u64*)(hring + (size_t)l * DEPTH * BB * HH);
    const u64* belowu = (const u64*)(hring + (size_t)(l - 1) * DEPTH * BB * HH);
    u64* const fastu  = hfast + (size_t)l * FDEPTH * SLOTU;

    // ---- prologue: stage below(0)/x(0) into hcB lower ----
    if (F == II) {
        #pragma unroll
        for (int i = 0; i < 2; ++i) {
            const int q = tid + i * NTH;
            if (q < BB * (II / 4)) {
                const int b = q >> 5, c4 = (q & 31) * 4;
                const float4 xv = *(const float4*)&x[((size_t)b * TT + 0) * II + c4];
                stage_x(sm, b, c4, xv);
            }
        }
    } else {
        u64 v[5];
        #pragma unroll
        for (int i = 0; i < 5; ++i) v[i] = ld_u64(belowu + tid + i * NTH);
        for (;;) {
            bool bad = false;
            #pragma unroll
            for (int i = 0; i < 5; ++i) bad |= ((u32)(v[i] >> 32) != 1u);
            if (__ballot(bad) == 0) break;
            __builtin_amdgcn_s_sleep(2);
            #pragma unroll
            for (int i = 0; i < 5; ++i) v[i] = ld_u64(belowu + tid + i * NTH);
        }
        asm volatile("" ::: "memory");
        #pragma unroll
        for (int i = 0; i < 5; ++i) {
            const int u = tid + i * NTH, sp = div40(u), q = u - 40 * sp;
            *(u32*)&sm.hcB[q >> 2][sp * 8 + (q & 3) * 2] = (u32)v[i];
        }
    }
    __syncthreads();

    bool fastok = true;   // sticky: persistent fast-path failure -> agent path
    u64 cv[10];
    u64 pvreg = 0;        // publishing lanes: pv of previous step (deferred safe pub)

    for (int t = 0; t < TT; ++t) {
        // ---- top: progress flag (wave2 lane0: off the gather waves' vm queues) ----
        if (F != II && t > 0 && tid == 128) st_cnt(&flags[l * 32 + s], t);
        // ---- flag PREFETCH (wave3): monotone counter -> sound lower bound ----
        int fpre = 0x7fffffff;
        if (wave == 3 && l < LAYERS - 1)
            fpre = ld_cnt(flags + (l + 1) * 32 + (tid & 31));

        // ---- C-issue (waves 0-1): 10 sc0 own-h loads, in flight under A-phase ----
        const u64* fslot = fastu + (size_t)((t - 1) & (FDEPTH - 1)) * SLOTU + tid;
        if (wave < 2 && t > 0 && fastok) ld10_issue(cv, fslot);
        // ---- deferred SAFE publish of h(t-1): issued AFTER the gather loads so
        //      the agent store is the NEWEST vm op -> excluded from vmcnt(1).
        //      No cycle: safe tag t depends only on OUR step t-1, not on peers. ----
        if (t > 0 && pubL)
            st_u64(ringu + (size_t)((t - 1) & (DEPTH - 1)) * SLOTU + s * 40 + pidx,
                   pvreg);

        // ---- F-issue (waves 2-3): below(t+1)/x(t+1) loads into regs; staged late ----
        u64 fv[10];
        float4 xq[3];
        const int fbase = tid - 128;
        if (wave >= 2 && t + 1 < TT) {
            if constexpr (F == II) {
                #pragma unroll
                for (int i = 0; i < 3; ++i) {
                    const int q = fbase + i * 128;
                    if (q < BB * (II / 4))
                        xq[i] = *(const float4*)&x[((size_t)(q >> 5) * TT + (t + 1)) * II
                                                   + (q & 31) * 4];
                }
            } else {
                const u64* src = belowu + (size_t)((t + 1) & (DEPTH - 1)) * SLOTU;
                #pragma unroll
                for (int i = 0; i < 10; ++i) fv[i] = ld_u64(src + fbase + i * 128);
            }
        }

        // ---- A: x-part MFMA from hcB lower (staged last step) ----
        f32x4 acc0 = {0.f, 0.f, 0.f, 0.f};
        f32x4 acc1 = {0.f, 0.f, 0.f, 0.f};
        #pragma unroll
        for (int p = 0; p < XP; ++p) {
            const int koff = (wave + 4 * p) * 32 + kgrp * 8;
            const bf16x8 bx = *(const bf16x8*)&sm.hcB[l15][koff];
            acc0 = MFMA16(whi[0][p], bx, acc0, 0, 0, 0);
            acc1 = MFMA16(whi[1][p], bx, acc1, 0, 0, 0);
            acc0 = MFMA16(wlo[0][p], bx, acc0, 0, 0, 0);
            acc1 = MFMA16(wlo[1][p], bx, acc1, 0, 0, 0);
            if (F == II) {   // layer 0: x lo-plane restores fp32-grade x precision
                const bf16x8 bl = *(const bf16x8*)&sm.xlo[l15][koff];
                acc0 = MFMA16(whi[0][p], bl, acc0, 0, 0, 0);
                acc1 = MFMA16(whi[1][p], bl, acc1, 0, 0, 0);
            }
        }

        // ---- C-complete (waves 0-1 only): tag-check + stage own-h upper ----
        if (wave < 2) {
            if (t > 0) {
                const u32 tg = (u32)t;
                bool ok = false;
                if (fastok) {
                    ld10_wait1(cv);   // vmcnt(1): loads done, store ack excluded
                    int it = 0;
                    for (;;) {
                        bool bad = false;
                        #pragma unroll
                        for (int i = 0; i < 10; ++i) bad |= ((u32)(cv[i] >> 32) != tg);
                        if (__ballot(bad) == 0) { ok = true; break; }
                        if (++it >= 12) break;
                        __builtin_amdgcn_s_sleep(1);
                        ld10_issue(cv, fslot);
                        ld10_wait(cv);
                    }
                    if (!ok) fastok = false;   // placement wrong/straggler: go agent
                }
                if (!ok) {
                    const u64* ownslot =
                        ringu + (size_t)((t - 1) & (DEPTH - 1)) * SLOTU + tid;
                    for (;;) {
                        #pragma unroll
                        for (int i = 0; i < 10; ++i) cv[i] = ld_u64(ownslot + i * 128);
                        bool bad = false;
                        #pragma unroll
                        for (int i = 0; i < 10; ++i) bad |= ((u32)(cv[i] >> 32) != tg);
                        if (__ballot(bad) == 0) break;
                        __builtin_amdgcn_s_sleep(1);
                    }
                    asm volatile("" ::: "memory");
                }
                #pragma unroll
                for (int i = 0; i < 10; ++i) {
                    const int u = tid + i * 128, sp = div40(u), q = u - 40 * sp;
                    *(u32*)&sm.hcB[q >> 2][F + sp * 8 + (q & 3) * 2] = (u32)cv[i];
                }
            } else {
                const u64* src = (const u64*)(h0 + (size_t)l * BB * HH);
                u64 v[10];
                #pragma unroll
                for (int i = 0; i < 10; ++i) v[i] = ld_u64(src + tid + i * 128);
                #pragma unroll
                for (int i = 0; i < 10; ++i) {
                    const int f = 2 * (tid + i * 128);
                    union { u64 u; float2 f2; } c; c.u = v[i];
                    const u32 a0 = bf16r(c.f2.x), a1 = bf16r(c.f2.y);
                    *(u32*)&sm.hcB[f >> 8][F + (f & 255)] = (a1 << 16) | a0;
                }
            }
        }
        __syncthreads();   // B1: own-h upper staged

        // ---- D: h-part MFMA ----
        #pragma unroll
        for (int p = XP; p < NKW; ++p) {
            const int koff = (wave + 4 * p) * 32 + kgrp * 8;
            const bf16x8 bx = *(const bf16x8*)&sm.hcB[l15][koff];
            acc0 = MFMA16(whi[0][p], bx, acc0, 0, 0, 0);
            acc1 = MFMA16(whi[1][p], bx, acc1, 0, 0, 0);
            acc0 = MFMA16(wlo[0][p], bx, acc0, 0, 0, 0);
            acc1 = MFMA16(wlo[1][p], bx, acc1, 0, 0, 0);
        }
        // C layout: col = l15 (batch), row = kgrp*4 + j (+ 16 per M-tile)
        *(f32x4*)&sm.red[wave][l15][kgrp * 4]      = acc0;
        *(f32x4*)&sm.red[wave][l15][16 + kgrp * 4] = acc1;

        // ---- F-complete (waves 2-3): tag-check + stage hcB lower for t+1 ----
        // (safe after B1: A(t) reads of lower are fully before B1)
        if (wave >= 2 && t + 1 < TT) {
            if constexpr (F == II) {
                #pragma unroll
                for (int i = 0; i < 3; ++i) {
                    const int q = fbase + i * 128;
                    if (q < BB * (II / 4))
                        stage_x(sm, q >> 5, (q & 31) * 4, xq[i]);
                }
            } else {
                const u64* src = belowu + (size_t)((t + 1) & (DEPTH - 1)) * SLOTU;
                const u32 tg = (u32)(t + 2);
                for (;;) {
                    bool bad = false;
                    #pragma unroll
                    for (int i = 0; i < 10; ++i) bad |= ((u32)(fv[i] >> 32) != tg);
                    if (__ballot(bad) == 0) break;
                    __builtin_amdgcn_s_sleep(2);
                    #pragma unroll
                    for (int i = 0; i < 10; ++i) fv[i] = ld_u64(src + fbase + i * 128);
                }
                asm volatile("" ::: "memory");
                #pragma unroll
                for (int i = 0; i < 10; ++i) {
                    const int u = fbase + i * 128;
                    const int sp = div40(u), q = u - 40 * sp;
                    *(u32*)&sm.hcB[q >> 2][sp * 8 + (q & 3) * 2] = (u32)fv[i];
                }
            }
        }
        // producer back-pressure: gates the safe-slot t&7 overwrite (deferred to
        // top of t+1, i.e. strictly after this gate). Prefetched flag is a sound
        // lower bound; the LLC poll runs only when it is stale (rare).
        if (wave == 3 && l < LAYERS - 1 && t >= 7 && t + 1 < TT) {
            const int tgt = (t - 7 > 1) ? (t - 7) : 1;
            if (__ballot(((tid & 63) < 32) && (fpre < tgt)) != 0)
                poll32(flags + (l + 1) * 32, tgt, true);
        }
        __syncthreads();   // B2: red partials + hcB lower(t+1) consistent

        // ---- epilogue (80 lanes, 1 column each): fast publish now, safe later ----
        float ch = 0.0f, cc = 0.0f;
        if (tid < 80) {
            float g4[4];
            #pragma unroll
            for (int g = 0; g < 4; ++g) {
                const int rl = g * 8 + ej;
                g4[g] = ((sm.red[0][eb][rl] + sm.red[1][eb][rl])
                       + (sm.red[2][eb][rl] + sm.red[3][eb][rl])) + sm.bias_s[rl];
            }
            float c = creg;
            c = fsig(g4[1]) * c + fsig(g4[0]) * ftanh(g4[2]);
            ch = fsig(g4[3]) * ftanh(c);
            cc = c;
            creg = c;
        }
        // cross-lane exchanges FULLY CONVERGED (shfl from inactive lane is UB)
        const float hn = __shfl_down(ch, 1);
        float cn = 0.0f;
        if (t == TT - 1) cn = __shfl_down(cc, 1);   // uniform branch: all lanes
        if (pubL) {
            const u64 pv = packh(ch, hn, (u32)(t + 1));
            if (t < TT - 1) {
                st_l2(fastu + (size_t)(t & (FDEPTH - 1)) * SLOTU + s * 40 + pidx, pv);
                pvreg = pv;   // safe publish deferred to top of step t+1
            } else {
                // final step: no later top -> immediate safe store
                if (l < LAYERS - 1)
                    st_u64(ringu + (size_t)(t & (DEPTH - 1)) * SLOTU + s * 40 + pidx,
                           pv);
                *(float2*)&out[((size_t)l * BB + eb) * HH + s * NCOL + ej] =
                    make_float2(cc, cn);
            }
        }
        // no B3: next A-phase reads hcB lower staged before B2; epilogue touches
        // only registers/global; red(t+1) stores are ordered by B1(t+1).
    }
}

__global__ __launch_bounds__(NTH, 1)
void lstm_persistent(const float* __restrict__ x, const float* __restrict__ h0,
                     const float* __restrict__ c0, const float* __restrict__ Wih0,
                     const float* __restrict__ Wih, const float* __restrict__ Whh,
                     const float* __restrict__ bih, const float* __restrict__ bhh,
                     float* __restrict__ out, int* flags, float* hring, u64* hfast)
{
    // layer = blockIdx & 7: round-robin block->XCD dispatch puts all 32 blocks
    // of a layer on one XCD -> own-h exchange in shared L2 (R4-R10 FETCH_SIZE
    // collapse 614->~130 MB confirms). Heuristic only; tags + sticky agent
    // fallback keep it correct under any placement.
    const int l = blockIdx.x & 7;
    const int s = blockIdx.x >> 3;
    if (l >= LAYERS) return;
    __shared__ Smem sm;
    if (l == 0)
        run_layer<12>(sm, l, s, x, h0, c0, Wih0, Wih, Whh, bih, bhh, out, flags,
                      hring, hfast);
    else
        run_layer<16>(sm, l, s, x, h0, c0, Wih0, Wih, Whh, bih, bhh, out, flags,
                      hring, hfast);
}

extern "C" void kernel_launch(void* const* d_in, const int* in_sizes, int n_in,
                              void* d_out, int out_size, void* d_ws, size_t ws_size,
                              hipStream_t stream) {
    const float* x    = (const float*)d_in[0];
    const float* h0   = (const float*)d_in[1];
    const float* c0   = (const float*)d_in[2];
    const float* Wih0 = (const float*)d_in[3];
    const float* Wih  = (const float*)d_in[4];
    const float* Whh  = (const float*)d_in[5];
    const float* bih  = (const float*)d_in[6];
    const float* bhh  = (const float*)d_in[7];
    float* out  = (float*)d_out;

    int*   flags = (int*)d_ws;                        // [L][32] progress ints
    float* hring = (float*)((char*)d_ws + 16384);     // [L][DEPTH] safe tagged slots
    u64*   hfast = (u64*)((char*)d_ws + 16384         // [L][FDEPTH] fast tagged slots
                          + (size_t)LAYERS * DEPTH * BB * HH * 4);
    (void)hipMemsetAsync(d_ws, 0, 16384, stream);
    hipLaunchKernelGGL(lstm_persistent, dim3(256), dim3(NTH), 0, stream,
                       x, h0, c0, Wih0, Wih, Whh, bih, bhh, out, flags, hring, hfast);
}

// Round 12
// 3529.334 us; speedup vs baseline: 1.1692x; 1.1692x over previous
//
#include <hip/hip_runtime.h>

#define LAYERS 6
#define BB 10
#define TT 2048
#define II 128
#define HH 256
#define DEPTH 8           // safe ring depth (power of 2)
#define FDEPTH 4          // fast ring depth (power of 2)
#define NTH 256
#define NROW 32           // gate rows per block (4 gates x 8 cols)
#define NCOL 8
#define SLOTU 1280        // u64 per layer-slot: 32 blocks x 40 tagged u64
#define KSTR 520          // hcB K-stride in bf16 (512 + 8 pad)
#define XSTR 136          // xlo K-stride in bf16 (128 + 8 pad)
#define RSTR 36           // red rloc-stride in floats

typedef unsigned long long u64;
typedef unsigned int u32;
typedef __attribute__((ext_vector_type(8))) short bf16x8;   // 8 bf16 = 4 VGPR
typedef __attribute__((ext_vector_type(4))) float f32x4;

#define MFMA16 __builtin_amdgcn_mfma_f32_16x16x32_bf16

struct __align__(16) Smem {
    short hcB[16][KSTR];     // bf16 [x/below-h | own-h] per batch row; rows 10..15 zero
    short xlo[16][XSTR];     // bf16 residual plane for layer-0 x (hi/lo split)
    float red[4][16][RSTR];  // per-wave K-partial gates: [wave][batch][rloc]
    float bias_s[NROW];
};

__device__ __forceinline__ float fsig(float x) { return 1.0f / (1.0f + __expf(-x)); }
__device__ __forceinline__ float ftanh(float x) {
    x = fminf(fmaxf(x, -15.0f), 15.0f);
    float e = __expf(2.0f * x);
    return (e - 1.0f) / (e + 1.0f);
}
__device__ __forceinline__ int ld_cnt(const int* p) {
    return __hip_atomic_load(p, __ATOMIC_RELAXED, __HIP_MEMORY_SCOPE_AGENT);
}
__device__ __forceinline__ void st_cnt(int* p, int v) {
    __hip_atomic_store(p, v, __ATOMIC_RELAXED, __HIP_MEMORY_SCOPE_AGENT);
}
__device__ __forceinline__ u64 ld_u64(const u64* p) {
    return __hip_atomic_load(p, __ATOMIC_RELAXED, __HIP_MEMORY_SCOPE_AGENT);
}
__device__ __forceinline__ void st_u64(u64* p, u64 v) {
    __hip_atomic_store(p, v, __ATOMIC_RELAXED, __HIP_MEMORY_SCOPE_AGENT);
}
// ---- XCD-local L2 exchange primitives ----
// producer: plain global_store -> lands in the XCD's shared L2 (stays dirty).
// consumer: sc0 load bypasses L1, reads the shared L2. Tags self-validate; the
// agent-scope safe ring (dual-published at the epilogue, same wave) is the
// correctness fallback under any block->XCD placement AND the primary l->l+1
// below-transport. R8/R9/R11 lesson: the agent store-ack on the gather wave is
// structurally irreducible — vmcnt retires in order; moving the store to other
// waves breaks load balance (R8) or fallback liveness (R9); deferring it delays
// the below-transport and burns back-pressure slack (R11).
__device__ __forceinline__ void st_l2(u64* p, u64 v) {
    asm volatile("global_store_dwordx2 %0, %1, off" :: "v"(p), "v"(v) : "memory");
}
// issue 10 sc0 loads (base + i*1024B), NO wait: latency hides under A-phase
__device__ __forceinline__ void ld10_issue(u64 v[10], const u64* p) {
    const u64* p4 = p + 4 * 128;
    const u64* p8 = p + 8 * 128;
    asm volatile(
        "global_load_dwordx2 %0, %10, off sc0\n\t"
        "global_load_dwordx2 %1, %10, off offset:1024 sc0\n\t"
        "global_load_dwordx2 %2, %10, off offset:2048 sc0\n\t"
        "global_load_dwordx2 %3, %10, off offset:3072 sc0\n\t"
        "global_load_dwordx2 %4, %11, off sc0\n\t"
        "global_load_dwordx2 %5, %11, off offset:1024 sc0\n\t"
        "global_load_dwordx2 %6, %11, off offset:2048 sc0\n\t"
        "global_load_dwordx2 %7, %11, off offset:3072 sc0\n\t"
        "global_load_dwordx2 %8, %12, off sc0\n\t"
        "global_load_dwordx2 %9, %12, off offset:1024 sc0\n\t"
        : "=&v"(v[0]), "=&v"(v[1]), "=&v"(v[2]), "=&v"(v[3]), "=&v"(v[4]),
          "=&v"(v[5]), "=&v"(v[6]), "=&v"(v[7]), "=&v"(v[8]), "=&v"(v[9])
        : "v"(p), "v"(p4), "v"(p8)
        : "memory");
}
// tied-operand wait: forces all uses of v[] to order after the waitcnt
__device__ __forceinline__ void ld10_wait(u64 v[10]) {
    asm volatile("s_waitcnt vmcnt(0)"
        : "+v"(v[0]), "+v"(v[1]), "+v"(v[2]), "+v"(v[3]), "+v"(v[4]),
          "+v"(v[5]), "+v"(v[6]), "+v"(v[7]), "+v"(v[8]), "+v"(v[9]) :: "memory");
    __builtin_amdgcn_sched_barrier(0);
}
__device__ __forceinline__ u32 bf16r(float v) {           // RNE float->bf16 bits
    u32 x = __float_as_uint(v);
    return (x + 0x7FFFu + ((x >> 16) & 1u)) >> 16;
}
// pack order: low u32 half = h0 (even col), high half = h1 (odd col): consumer
// stores raw (u32)v into LDS and gets k-ascending bf16 pairs.
__device__ __forceinline__ u64 packh(float h0, float h1, u32 tag) {
    return ((u64)tag << 32) | ((u64)bf16r(h1) << 16) | (u64)bf16r(h0);
}
// u/40 exact for u < 262144
__device__ __forceinline__ int div40(int u) { return (int)(((unsigned)u * 52429u) >> 21); }

// back-pressure poll: all 32 ints on one 128B line >= tgt
__device__ __forceinline__ void poll32(const int* base, int tgt, bool sleep) {
    const int lane = threadIdx.x & 63;
    const int* p = base + (lane & 31);
    for (;;) {
        int v = ld_cnt(p);
        if (__ballot((lane < 32) && (v < tgt)) == 0) break;
        if (sleep) __builtin_amdgcn_s_sleep(2);
    }
    asm volatile("" ::: "memory");
}

// stage 4 fp32 x values -> bf16 hi plane + bf16 lo (residual) plane
__device__ __forceinline__ void stage_x(Smem& sm, int b, int c4, float4 xv) {
    const u32 h0 = bf16r(xv.x), h1 = bf16r(xv.y), h2 = bf16r(xv.z), h3 = bf16r(xv.w);
    *(u32*)&sm.hcB[b][c4]     = (h1 << 16) | h0;
    *(u32*)&sm.hcB[b][c4 + 2] = (h3 << 16) | h2;
    const u32 r0 = bf16r(xv.x - __uint_as_float(h0 << 16));
    const u32 r1 = bf16r(xv.y - __uint_as_float(h1 << 16));
    const u32 r2 = bf16r(xv.z - __uint_as_float(h2 << 16));
    const u32 r3 = bf16r(xv.w - __uint_as_float(h3 << 16));
    *(u32*)&sm.xlo[b][c4]     = (r1 << 16) | r0;
    *(u32*)&sm.xlo[b][c4 + 2] = (r3 << 16) | r2;
}

// NKT: 12 -> K=384 (layer 0), 16 -> K=512 (layers 1..5)
template <int NKT>
__device__ void run_layer(Smem& sm, int l, int s,
                          const float* __restrict__ x,
                          const float* __restrict__ h0,
                          const float* __restrict__ c0,
                          const float* __restrict__ Wih0,
                          const float* __restrict__ Wih,
                          const float* __restrict__ Whh,
                          const float* __restrict__ bih,
                          const float* __restrict__ bhh,
                          float* __restrict__ out,
                          int* flags, float* hring, u64* hfast)
{
    constexpr int K   = NKT * 32;
    constexpr int F   = K - HH;       // x-part size: 128 or 256
    constexpr int NKW = NKT / 4;      // K-tiles per wave (3 or 4)
    constexpr int XP  = NKW - 2;      // x-region K-tiles per wave (1 or 2)

    const int tid  = threadIdx.x;
    const int wave = tid >> 6;
    const int l15  = tid & 15;        // MFMA: A row / B col (batch) / C col
    const int kgrp = (tid >> 4) & 3;  // MFMA: K-group within tile
    const int eb   = tid >> 3;        // epilogue batch  (tid < 80)
    const int ej   = tid & 7;         // epilogue column (tid < 80)

    const float* WihL = (F == II) ? Wih0 : (Wih + (size_t)(l - 1) * 4 * HH * HH);
    const float* WhhL = Whh + (size_t)l * 4 * HH * HH;

    // ---- weight fragments, hi/lo split, VGPR-resident ----
    // wave w owns K-tiles {w + 4p}; p < XP is x-region, rest is h-region.
    bf16x8 whi[2][NKW], wlo[2][NKW];
    #pragma unroll
    for (int m = 0; m < 2; ++m) {
        const int rloc = m * 16 + l15;
        const int gr = (rloc >> 3) * HH + s * NCOL + (rloc & 7);
        const float* rowI = WihL + (size_t)gr * F;
        const float* rowH = WhhL + (size_t)gr * HH;
        #pragma unroll
        for (int p = 0; p < NKW; ++p) {
            const int kb = (wave + 4 * p) * 32 + kgrp * 8;   // multiple of 8; F%8==0
            const float* src = (kb < F) ? (rowI + kb) : (rowH + (kb - F));
            const float4 va = *(const float4*)src;
            const float4 vb = *(const float4*)(src + 4);
            const float v[8] = {va.x, va.y, va.z, va.w, vb.x, vb.y, vb.z, vb.w};
            #pragma unroll
            for (int j = 0; j < 8; ++j) {
                const u32 hi = bf16r(v[j]);
                whi[m][p][j] = (short)hi;
                wlo[m][p][j] = (short)bf16r(v[j] - __uint_as_float(hi << 16));
            }
        }
    }
    if (tid < NROW) {
        const int gr = (tid >> 3) * HH + s * NCOL + (tid & 7);
        sm.bias_s[tid] = bih[l * 4 * HH + gr] + bhh[l * 4 * HH + gr];
    }
    // c-state lives in a register: 80 lanes, 1 column each (b = eb, jj = ej)
    float creg = 0.0f;
    if (tid < 80)
        creg = c0[((size_t)l * BB + eb) * HH + s * NCOL + ej];
    {   // zero batch rows 10..15 (MFMA N=16 padding is inert; never written again)
        u32* z1 = (u32*)&sm.hcB[10][0];
        for (int i = tid; i < 6 * KSTR / 2; i += NTH) z1[i] = 0;
        u32* z2 = (u32*)&sm.xlo[10][0];
        for (int i = tid; i < 6 * XSTR / 2; i += NTH) z2[i] = 0;
    }

    u64* const ringu  = (u64*)(hring + (size_t)l * DEPTH * BB * HH);
    const u64* belowu = (const u64*)(hring + (size_t)(l - 1) * DEPTH * BB * HH);
    u64* const fastu  = hfast + (size_t)l * FDEPTH * SLOTU;

    // ---- prologue: stage below(0)/x(0) into hcB lower ----
    if (F == II) {
        #pragma unroll
        for (int i = 0; i < 2; ++i) {
            const int q = tid + i * NTH;
            if (q < BB * (II / 4)) {
                const int b = q >> 5, c4 = (q & 31) * 4;
                const float4 xv = *(const float4*)&x[((size_t)b * TT + 0) * II + c4];
                stage_x(sm, b, c4, xv);
            }
        }
    } else {
        u64 v[5];
        #pragma unroll
        for (int i = 0; i < 5; ++i) v[i] = ld_u64(belowu + tid + i * NTH);
        for (;;) {
            bool bad = false;
            #pragma unroll
            for (int i = 0; i < 5; ++i) bad |= ((u32)(v[i] >> 32) != 1u);
            if (__ballot(bad) == 0) break;
            __builtin_amdgcn_s_sleep(2);
            #pragma unroll
            for (int i = 0; i < 5; ++i) v[i] = ld_u64(belowu + tid + i * NTH);
        }
        asm volatile("" ::: "memory");
        #pragma unroll
        for (int i = 0; i < 5; ++i) {
            const int u = tid + i * NTH, sp = div40(u), q = u - 40 * sp;
            *(u32*)&sm.hcB[q >> 2][sp * 8 + (q & 3) * 2] = (u32)v[i];
        }
    }
    __syncthreads();

    bool fastok = true;   // sticky: persistent fast-path failure -> agent path
    u64 cv[10];

    for (int t = 0; t < TT; ++t) {
        // ---- top: progress flag (wave2 lane0: off the gather waves' vm queues) ----
        if (F != II && t > 0 && tid == 128) st_cnt(&flags[l * 32 + s], t);
        // ---- flag PREFETCH (wave3): monotone counter -> the value loaded here
        //      is a sound lower bound at the pre-B2 gate; full poll only if stale ----
        int fpre = 0x7fffffff;
        if (wave == 3 && l < LAYERS - 1)
            fpre = ld_cnt(flags + (l + 1) * 32 + (tid & 31));

        // ---- C-issue (waves 0-1): 10 sc0 own-h loads, in flight under A-phase ----
        const u64* fslot = fastu + (size_t)((t - 1) & (FDEPTH - 1)) * SLOTU + tid;
        if (wave < 2 && t > 0 && fastok) ld10_issue(cv, fslot);

        // ---- F-issue (waves 2-3): below(t+1)/x(t+1) loads into regs; staged late ----
        u64 fv[10];
        float4 xq[3];
        const int fbase = tid - 128;
        if (wave >= 2 && t + 1 < TT) {
            if constexpr (F == II) {
                #pragma unroll
                for (int i = 0; i < 3; ++i) {
                    const int q = fbase + i * 128;
                    if (q < BB * (II / 4))
                        xq[i] = *(const float4*)&x[((size_t)(q >> 5) * TT + (t + 1)) * II
                                                   + (q & 31) * 4];
                }
            } else {
                const u64* src = belowu + (size_t)((t + 1) & (DEPTH - 1)) * SLOTU;
                #pragma unroll
                for (int i = 0; i < 10; ++i) fv[i] = ld_u64(src + fbase + i * 128);
            }
        }

        // ---- A: x-part MFMA from hcB lower (staged last step) ----
        f32x4 acc0 = {0.f, 0.f, 0.f, 0.f};
        f32x4 acc1 = {0.f, 0.f, 0.f, 0.f};
        #pragma unroll
        for (int p = 0; p < XP; ++p) {
            const int koff = (wave + 4 * p) * 32 + kgrp * 8;
            const bf16x8 bx = *(const bf16x8*)&sm.hcB[l15][koff];
            acc0 = MFMA16(whi[0][p], bx, acc0, 0, 0, 0);
            acc1 = MFMA16(whi[1][p], bx, acc1, 0, 0, 0);
            acc0 = MFMA16(wlo[0][p], bx, acc0, 0, 0, 0);
            acc1 = MFMA16(wlo[1][p], bx, acc1, 0, 0, 0);
            if (F == II) {   // layer 0: x lo-plane restores fp32-grade x precision
                const bf16x8 bl = *(const bf16x8*)&sm.xlo[l15][koff];
                acc0 = MFMA16(whi[0][p], bl, acc0, 0, 0, 0);
                acc1 = MFMA16(whi[1][p], bl, acc1, 0, 0, 0);
            }
        }

        // ---- C-complete (waves 0-1 only): tag-check + stage own-h upper ----
        if (wave < 2) {
            if (t > 0) {
                const u32 tg = (u32)t;
                bool ok = false;
                if (fastok) {
                    ld10_wait(cv);
                    int it = 0;
                    for (;;) {
                        bool bad = false;
                        #pragma unroll
                        for (int i = 0; i < 10; ++i) bad |= ((u32)(cv[i] >> 32) != tg);
                        if (__ballot(bad) == 0) { ok = true; break; }
                        if (++it >= 12) break;
                        __builtin_amdgcn_s_sleep(1);
                        ld10_issue(cv, fslot);
                        ld10_wait(cv);
                    }
                    if (!ok) fastok = false;   // placement wrong/straggler: go agent
                }
                if (!ok) {
                    const u64* ownslot =
                        ringu + (size_t)((t - 1) & (DEPTH - 1)) * SLOTU + tid;
                    for (;;) {
                        #pragma unroll
                        for (int i = 0; i < 10; ++i) cv[i] = ld_u64(ownslot + i * 128);
                        bool bad = false;
                        #pragma unroll
                        for (int i = 0; i < 10; ++i) bad |= ((u32)(cv[i] >> 32) != tg);
                        if (__ballot(bad) == 0) break;
                        __builtin_amdgcn_s_sleep(1);
                    }
                    asm volatile("" ::: "memory");
                }
                #pragma unroll
                for (int i = 0; i < 10; ++i) {
                    const int u = tid + i * 128, sp = div40(u), q = u - 40 * sp;
                    *(u32*)&sm.hcB[q >> 2][F + sp * 8 + (q & 3) * 2] = (u32)cv[i];
                }
            } else {
                const u64* src = (const u64*)(h0 + (size_t)l * BB * HH);
                u64 v[10];
                #pragma unroll
                for (int i = 0; i < 10; ++i) v[i] = ld_u64(src + tid + i * 128);
                #pragma unroll
                for (int i = 0; i < 10; ++i) {
                    const int f = 2 * (tid + i * 128);
                    union { u64 u; float2 f2; } c; c.u = v[i];
                    const u32 a0 = bf16r(c.f2.x), a1 = bf16r(c.f2.y);
                    *(u32*)&sm.hcB[f >> 8][F + (f & 255)] = (a1 << 16) | a0;
                }
            }
        }
        __syncthreads();   // B1: own-h upper staged

        // ---- D: h-part MFMA ----
        #pragma unroll
        for (int p = XP; p < NKW; ++p) {
            const int koff = (wave + 4 * p) * 32 + kgrp * 8;
            const bf16x8 bx = *(const bf16x8*)&sm.hcB[l15][koff];
            acc0 = MFMA16(whi[0][p], bx, acc0, 0, 0, 0);
            acc1 = MFMA16(whi[1][p], bx, acc1, 0, 0, 0);
            acc0 = MFMA16(wlo[0][p], bx, acc0, 0, 0, 0);
            acc1 = MFMA16(wlo[1][p], bx, acc1, 0, 0, 0);
        }
        // C layout: col = l15 (batch), row = kgrp*4 + j (+ 16 per M-tile)
        *(f32x4*)&sm.red[wave][l15][kgrp * 4]      = acc0;
        *(f32x4*)&sm.red[wave][l15][16 + kgrp * 4] = acc1;

        // ---- F-complete (waves 2-3): tag-check + stage hcB lower for t+1 ----
        // (safe after B1: A(t) reads of lower are fully before B1)
        if (wave >= 2 && t + 1 < TT) {
            if constexpr (F == II) {
                #pragma unroll
                for (int i = 0; i < 3; ++i) {
                    const int q = fbase + i * 128;
                    if (q < BB * (II / 4))
                        stage_x(sm, q >> 5, (q & 31) * 4, xq[i]);
                }
            } else {
                const u64* src = belowu + (size_t)((t + 1) & (DEPTH - 1)) * SLOTU;
                const u32 tg = (u32)(t + 2);
                for (;;) {
                    bool bad = false;
                    #pragma unroll
                    for (int i = 0; i < 10; ++i) bad |= ((u32)(fv[i] >> 32) != tg);
                    if (__ballot(bad) == 0) break;
                    __builtin_amdgcn_s_sleep(2);
                    #pragma unroll
                    for (int i = 0; i < 10; ++i) fv[i] = ld_u64(src + fbase + i * 128);
                }
                asm volatile("" ::: "memory");
                #pragma unroll
                for (int i = 0; i < 10; ++i) {
                    const int u = fbase + i * 128;
                    const int sp = div40(u), q = u - 40 * sp;
                    *(u32*)&sm.hcB[q >> 2][sp * 8 + (q & 3) * 2] = (u32)fv[i];
                }
            }
        }
        // producer back-pressure: gates epilogue(t)'s overwrite of safe slot t&7
        // (old tag t-7): consumed by l+1 once flags[l+1] >= t-8 (tgt t-7 is 1
        // conservative). Prefetched flag is a sound lower bound; the LLC poll
        // runs only when it is stale (rare: flags[l+1] ~ t-2 >> t-7).
        if (wave == 3 && l < LAYERS - 1 && t >= 7 && t + 1 < TT) {
            const int tgt = (t - 7 > 1) ? (t - 7) : 1;
            if (__ballot(((tid & 63) < 32) && (fpre < tgt)) != 0)
                poll32(flags + (l + 1) * 32, tgt, true);
        }
        __syncthreads();   // B2: red partials + hcB lower(t+1) consistent

        // ---- epilogue (80 lanes, 1 column each) + immediate dual publish ----
        float ch = 0.0f, cc = 0.0f;
        if (tid < 80) {
            float g4[4];
            #pragma unroll
            for (int g = 0; g < 4; ++g) {
                const int rl = g * 8 + ej;
                g4[g] = ((sm.red[0][eb][rl] + sm.red[1][eb][rl])
                       + (sm.red[2][eb][rl] + sm.red[3][eb][rl])) + sm.bias_s[rl];
            }
            float c = creg;
            c = fsig(g4[1]) * c + fsig(g4[0]) * ftanh(g4[2]);
            ch = fsig(g4[3]) * ftanh(c);
            cc = c;
            creg = c;
        }
        // cross-lane exchanges FULLY CONVERGED (shfl from inactive lane is UB)
        const float hn = __shfl_down(ch, 1);
        float cn = 0.0f;
        if (t == TT - 1) cn = __shfl_down(cc, 1);   // uniform branch: all lanes
        if (tid < 80 && (ej & 1) == 0) {
            const int idx = eb * 4 + (ej >> 1);
            const u64 pv = packh(ch, hn, (u32)(t + 1));
            if (t < TT - 1) {
                st_l2(fastu + (size_t)(t & (FDEPTH - 1)) * SLOTU + s * 40 + idx, pv);
                st_u64(ringu + (size_t)(t & (DEPTH - 1)) * SLOTU + s * 40 + idx, pv);
            } else {
                if (l < LAYERS - 1)
                    st_u64(ringu + (size_t)(t & (DEPTH - 1)) * SLOTU + s * 40 + idx, pv);
                *(float2*)&out[((size_t)l * BB + eb) * HH + s * NCOL + ej] =
                    make_float2(cc, cn);
            }
        }
        // no B3: next A-phase reads hcB lower staged before B2; epilogue touches
        // only registers/global; red(t+1) stores are ordered by B1(t+1).
    }
}

__global__ __launch_bounds__(NTH, 1)
void lstm_persistent(const float* __restrict__ x, const float* __restrict__ h0,
                     const float* __restrict__ c0, const float* __restrict__ Wih0,
                     const float* __restrict__ Wih, const float* __restrict__ Whh,
                     const float* __restrict__ bih, const float* __restrict__ bhh,
                     float* __restrict__ out, int* flags, float* hring, u64* hfast)
{
    // layer = blockIdx & 7: round-robin block->XCD dispatch puts all 32 blocks
    // of a layer on one XCD -> own-h exchange in shared L2 (R4-R10 FETCH_SIZE
    // collapse 614->~130 MB confirms). Heuristic only; tags + sticky agent
    // fallback keep it correct under any placement.
    const int l = blockIdx.x & 7;
    const int s = blockIdx.x >> 3;
    if (l >= LAYERS) return;
    __shared__ Smem sm;
    if (l == 0)
        run_layer<12>(sm, l, s, x, h0, c0, Wih0, Wih, Whh, bih, bhh, out, flags,
                      hring, hfast);
    else
        run_layer<16>(sm, l, s, x, h0, c0, Wih0, Wih, Whh, bih, bhh, out, flags,
                      hring, hfast);
}

extern "C" void kernel_launch(void* const* d_in, const int* in_sizes, int n_in,
                              void* d_out, int out_size, void* d_ws, size_t ws_size,
                              hipStream_t stream) {
    const float* x    = (const float*)d_in[0];
    const float* h0   = (const float*)d_in[1];
    const float* c0   = (const float*)d_in[2];
    const float* Wih0 = (const float*)d_in[3];
    const float* Wih  = (const float*)d_in[4];
    const float* Whh  = (const float*)d_in[5];
    const float* bih  = (const float*)d_in[6];
    const float* bhh  = (const float*)d_in[7];
    float* out  = (float*)d_out;

    int*   flags = (int*)d_ws;                        // [L][32] progress ints
    float* hring = (float*)((char*)d_ws + 16384);     // [L][DEPTH] safe tagged slots
    u64*   hfast = (u64*)((char*)d_ws + 16384         // [L][FDEPTH] fast tagged slots
                          + (size_t)LAYERS * DEPTH * BB * HH * 4);
    (void)hipMemsetAsync(d_ws, 0, 16384, stream);
    hipLaunchKernelGGL(lstm_persistent, dim3(256), dim3(NTH), 0, stream,
                       x, h0, c0, Wih0, Wih, Whh, bih, bhh, out, flags, hring, hfast);
}